// Round 2
// baseline (7203.390 us; speedup 1.0000x reference)
//
#include <hip/hip_runtime.h>
#include <math.h>

#define BB 8
#define CC 512
#define GG 32
#define CPG 16
#define NN 4096
#define EPSV 1e-5f

// ---------------------------------------------------------------------------
// Kernel 1: GroupNorm statistics -> per (b,c) scale/shift so that
//   hn[b,c,i] = x[b,c,i]*scale[b,c] + shift[b,c]
// One block per (b, group). All 8 batches at once (tiny output: 16 KB x2).
// ---------------------------------------------------------------------------
__global__ __launch_bounds__(256) void gn_stats(
    const float* __restrict__ x, const float* __restrict__ gamma,
    const float* __restrict__ beta, float* __restrict__ scale,
    float* __restrict__ shift) {
  int bg = blockIdx.x;  // 0..BB*GG-1
  int b = bg / GG, g = bg % GG;
  const float* base = x + ((size_t)b * CC + (size_t)g * CPG) * NN;
  int t = threadIdx.x;
  float s = 0.f, ss = 0.f;
  const float4* b4 = (const float4*)base;
  const int n4 = CPG * NN / 4;  // 16384 float4
  for (int idx = t; idx < n4; idx += 256) {
    float4 v = b4[idx];
    s += v.x + v.y + v.z + v.w;
    ss += v.x * v.x + v.y * v.y + v.z * v.z + v.w * v.w;
  }
  __shared__ float ls[256], lss[256];
  ls[t] = s; lss[t] = ss;
  __syncthreads();
  for (int o = 128; o > 0; o >>= 1) {
    if (t < o) { ls[t] += ls[t + o]; lss[t] += lss[t + o]; }
    __syncthreads();
  }
  if (t < CPG) {
    const float invn = 1.0f / (float)(CPG * NN);
    float mean = ls[0] * invn;
    float var = lss[0] * invn - mean * mean;
    float rstd = rsqrtf(var + EPSV);
    int c = g * CPG + t;
    float sc = rstd * gamma[c];
    scale[b * CC + c] = sc;
    shift[b * CC + c] = beta[c] - mean * sc;
  }
}

// ---------------------------------------------------------------------------
// Kernel 2: per-batch 1x1 conv GEMM: out[m,n] = sum_k W[m,k]*Bop[k,n] (+bias)
//   FUSE_GN: Bop element = x*scaleB+shiftB (GroupNorm applied on the fly)
//   RESID:   epilogue adds xres (residual) for the output projection
// All pointers are already offset to the current batch.
// Tiles: 64x64, BK=16, 256 threads, 4x4 micro-tile per thread.
// ---------------------------------------------------------------------------
template <bool FUSE_GN, bool RESID>
__global__ __launch_bounds__(256) void conv_gemm(
    const float* __restrict__ Wm, const float* __restrict__ bias,
    const float* __restrict__ Bsrc, const float* __restrict__ scaleB,
    const float* __restrict__ shiftB, const float* __restrict__ xres,
    float* __restrict__ out) {
  int m0 = blockIdx.y * 64;
  int n0 = blockIdx.x * 64;
  __shared__ float At[16][65];  // At[k][m] (+1 pad)
  __shared__ float Bt[16][64];  // Bt[k][n]
  int t = threadIdx.x;
  int tx = t & 15, ty = t >> 4;
  float acc[4][4] = {};
  for (int k0 = 0; k0 < CC; k0 += 16) {
#pragma unroll
    for (int r = 0; r < 4; ++r) {
      int idx = t + r * 256;
      int m = idx >> 4, k = idx & 15;
      At[k][m] = Wm[(size_t)(m0 + m) * CC + k0 + k];
    }
#pragma unroll
    for (int r = 0; r < 4; ++r) {
      int idx = t + r * 256;
      int n = idx & 63, k = idx >> 6;
      int c = k0 + k;
      float v = Bsrc[(size_t)c * NN + n0 + n];
      if (FUSE_GN) v = v * scaleB[c] + shiftB[c];
      Bt[k][n] = v;
    }
    __syncthreads();
#pragma unroll
    for (int k = 0; k < 16; ++k) {
      float a[4], bv[4];
#pragma unroll
      for (int i = 0; i < 4; ++i) a[i] = At[k][ty + 16 * i];
#pragma unroll
      for (int j = 0; j < 4; ++j) bv[j] = Bt[k][tx + 16 * j];
#pragma unroll
      for (int i = 0; i < 4; ++i)
#pragma unroll
        for (int j = 0; j < 4; ++j) acc[i][j] += a[i] * bv[j];
    }
    __syncthreads();
  }
#pragma unroll
  for (int i = 0; i < 4; ++i) {
    int m = m0 + ty + 16 * i;
    float bval = bias[m];
#pragma unroll
    for (int j = 0; j < 4; ++j) {
      int n = n0 + tx + 16 * j;
      size_t off = (size_t)m * NN + n;
      float r = acc[i][j] + bval;
      if (RESID) r += xres[off];
      out[off] = r;
    }
  }
}

// ---------------------------------------------------------------------------
// Kernel 3: S[i,j] = (1/sqrt(C)) * sum_c q[c,i]*k[c,j]   (one batch)
// Both operands are K-major [C][N] -> coalesced 64-wide tile loads.
// ---------------------------------------------------------------------------
__global__ __launch_bounds__(256) void qk_gemm(
    const float* __restrict__ q, const float* __restrict__ k,
    float* __restrict__ S) {
  int i0 = blockIdx.y * 64, j0 = blockIdx.x * 64;
  __shared__ float Qt[16][64];
  __shared__ float Kt[16][64];
  int t = threadIdx.x, tx = t & 15, ty = t >> 4;
  float acc[4][4] = {};
  for (int c0 = 0; c0 < CC; c0 += 16) {
#pragma unroll
    for (int r = 0; r < 4; ++r) {
      int idx = t + r * 256;
      int n = idx & 63, c = idx >> 6;
      Qt[c][n] = q[(size_t)(c0 + c) * NN + i0 + n];
      Kt[c][n] = k[(size_t)(c0 + c) * NN + j0 + n];
    }
    __syncthreads();
#pragma unroll
    for (int c = 0; c < 16; ++c) {
      float a[4], bv[4];
#pragma unroll
      for (int i = 0; i < 4; ++i) a[i] = Qt[c][ty + 16 * i];
#pragma unroll
      for (int j = 0; j < 4; ++j) bv[j] = Kt[c][tx + 16 * j];
#pragma unroll
      for (int i = 0; i < 4; ++i)
#pragma unroll
        for (int j = 0; j < 4; ++j) acc[i][j] += a[i] * bv[j];
    }
    __syncthreads();
  }
  const float rs = 0.04419417382415922f;  // 1/sqrt(512)
#pragma unroll
  for (int i = 0; i < 4; ++i)
#pragma unroll
    for (int j = 0; j < 4; ++j)
      S[(size_t)(i0 + ty + 16 * i) * NN + j0 + tx + 16 * j] = acc[i][j] * rs;
}

// ---------------------------------------------------------------------------
// Kernel 4: row softmax over j for one batch's S [NN x NN]
// ---------------------------------------------------------------------------
__global__ __launch_bounds__(256) void softmax_rows(float* __restrict__ S) {
  int i = blockIdx.x;
  float4* r4 = (float4*)(S + (size_t)i * NN);
  int t = threadIdx.x;
  float4 vals[4];
  float m = -1e30f;
#pragma unroll
  for (int r = 0; r < 4; ++r) {
    float4 v = r4[t + r * 256];
    vals[r] = v;
    m = fmaxf(m, fmaxf(fmaxf(v.x, v.y), fmaxf(v.z, v.w)));
  }
  __shared__ float red[256];
  red[t] = m;
  __syncthreads();
  for (int o = 128; o > 0; o >>= 1) {
    if (t < o) red[t] = fmaxf(red[t], red[t + o]);
    __syncthreads();
  }
  m = red[0];
  __syncthreads();
  float s = 0.f;
#pragma unroll
  for (int r = 0; r < 4; ++r) {
    vals[r].x = __expf(vals[r].x - m);
    vals[r].y = __expf(vals[r].y - m);
    vals[r].z = __expf(vals[r].z - m);
    vals[r].w = __expf(vals[r].w - m);
    s += vals[r].x + vals[r].y + vals[r].z + vals[r].w;
  }
  red[t] = s;
  __syncthreads();
  for (int o = 128; o > 0; o >>= 1) {
    if (t < o) red[t] += red[t + o];
    __syncthreads();
  }
  float inv = 1.0f / red[0];
#pragma unroll
  for (int r = 0; r < 4; ++r) {
    vals[r].x *= inv; vals[r].y *= inv; vals[r].z *= inv; vals[r].w *= inv;
    r4[t + r * 256] = vals[r];
  }
}

// ---------------------------------------------------------------------------
// Kernel 5: O[c,i] = sum_j V[c,j] * P[i,j]   (one batch)
// A (V) and B (P^T) both need 16-wide transposed tile loads (pad +1).
// ---------------------------------------------------------------------------
__global__ __launch_bounds__(256) void pv_gemm(
    const float* __restrict__ v, const float* __restrict__ P,
    float* __restrict__ o) {
  int n0 = blockIdx.x * 64;  // i
  int m0 = blockIdx.y * 64;  // c
  __shared__ float Vt[16][65];  // Vt[k=j][m=c]
  __shared__ float Pt[16][65];  // Pt[k=j][n=i]
  int t = threadIdx.x, tx = t & 15, ty = t >> 4;
  float acc[4][4] = {};
  for (int k0 = 0; k0 < NN; k0 += 16) {
#pragma unroll
    for (int r = 0; r < 4; ++r) {
      int idx = t + r * 256;
      int m = idx >> 4, k = idx & 15;
      Vt[k][m] = v[(size_t)(m0 + m) * NN + k0 + k];
      Pt[k][m] = P[(size_t)(n0 + m) * NN + k0 + k];
    }
    __syncthreads();
#pragma unroll
    for (int k = 0; k < 16; ++k) {
      float a[4], bv[4];
#pragma unroll
      for (int i = 0; i < 4; ++i) a[i] = Vt[k][ty + 16 * i];
#pragma unroll
      for (int j = 0; j < 4; ++j) bv[j] = Pt[k][tx + 16 * j];
#pragma unroll
      for (int i = 0; i < 4; ++i)
#pragma unroll
        for (int j = 0; j < 4; ++j) acc[i][j] += a[i] * bv[j];
    }
    __syncthreads();
  }
#pragma unroll
  for (int i = 0; i < 4; ++i)
#pragma unroll
    for (int j = 0; j < 4; ++j)
      o[(size_t)(m0 + ty + 16 * i) * NN + n0 + tx + 16 * j] = acc[i][j];
}

// ---------------------------------------------------------------------------
// Per-batch pipeline to keep d_ws usage at ~96 MiB (R1's 320 MiB likely
// overflowed ws_size -> GPU memory fault -> abort).
// ---------------------------------------------------------------------------
extern "C" void kernel_launch(void* const* d_in, const int* in_sizes, int n_in,
                              void* d_out, int out_size, void* d_ws,
                              size_t ws_size, hipStream_t stream) {
  const float* x = (const float*)d_in[0];
  const float* gamma = (const float*)d_in[1];
  const float* beta = (const float*)d_in[2];
  const float* Wq = (const float*)d_in[3];
  const float* bq = (const float*)d_in[4];
  const float* Wk = (const float*)d_in[5];
  const float* bk = (const float*)d_in[6];
  const float* Wv = (const float*)d_in[7];
  const float* bv = (const float*)d_in[8];
  const float* Wp = (const float*)d_in[9];
  const float* bp = (const float*)d_in[10];
  float* out = (float*)d_out;

  float* ws = (float*)d_ws;
  const size_t CN = (size_t)CC * NN;   // 2,097,152 floats = 8 MiB
  float* q = ws;                       // CN (per-batch, reused)
  float* k = q + CN;                   // CN
  float* v = k + CN;                   // CN
  float* o = v + CN;                   // CN
  float* S = o + CN;                   // NN*NN = 64 MiB (per-batch, reused)
  float* scale = S + (size_t)NN * NN;  // BB*CC
  float* shift = scale + BB * CC;      // BB*CC
  // total: 4*CN + NN*NN + 2*BB*CC floats = 96 MiB + 32 KiB

  gn_stats<<<BB * GG, 256, 0, stream>>>(x, gamma, beta, scale, shift);

  dim3 gConv(NN / 64, CC / 64);
  dim3 gQK(NN / 64, NN / 64);
  for (int b = 0; b < BB; ++b) {
    const float* xb = x + (size_t)b * CN;
    const float* scb = scale + b * CC;
    const float* shb = shift + b * CC;
    conv_gemm<true, false><<<gConv, 256, 0, stream>>>(Wq, bq, xb, scb, shb,
                                                      nullptr, q);
    conv_gemm<true, false><<<gConv, 256, 0, stream>>>(Wk, bk, xb, scb, shb,
                                                      nullptr, k);
    conv_gemm<true, false><<<gConv, 256, 0, stream>>>(Wv, bv, xb, scb, shb,
                                                      nullptr, v);
    qk_gemm<<<gQK, 256, 0, stream>>>(q, k, S);
    softmax_rows<<<NN, 256, 0, stream>>>(S);
    pv_gemm<<<gConv, 256, 0, stream>>>(v, S, o);
    conv_gemm<false, true><<<gConv, 256, 0, stream>>>(
        Wp, bp, o, nullptr, nullptr, xb, out + (size_t)b * CN);
  }
}

// Round 3
// 1353.853 us; speedup vs baseline: 5.3207x; 5.3207x over previous
//
#include <hip/hip_runtime.h>
#include <math.h>

#define BB 8
#define CC 512
#define GG 32
#define CPG 16
#define NN 4096
#define EPSV 1e-5f

typedef __attribute__((ext_vector_type(8))) short bf16x8;
typedef __attribute__((ext_vector_type(4))) float f32x4;

__device__ __forceinline__ unsigned short f2bf(float f) {
  union { float f; unsigned u; } v;
  v.f = f;
  unsigned r = v.u + 0x7FFFu + ((v.u >> 16) & 1u);  // RNE
  return (unsigned short)(r >> 16);
}
__device__ __forceinline__ float bf2f(unsigned short u) {
  union { unsigned u; float f; } v;
  v.u = ((unsigned)u) << 16;
  return v.f;
}

// ---------------------------------------------------------------------------
// GroupNorm stats -> per (b,c) scale/shift (fp32, as R2)
// ---------------------------------------------------------------------------
__global__ __launch_bounds__(256) void gn_stats(
    const float* __restrict__ x, const float* __restrict__ gamma,
    const float* __restrict__ beta, float* __restrict__ scale,
    float* __restrict__ shift) {
  int bg = blockIdx.x;
  int b = bg / GG, g = bg % GG;
  const float* base = x + ((size_t)b * CC + (size_t)g * CPG) * NN;
  int t = threadIdx.x;
  float s = 0.f, ss = 0.f;
  const float4* b4 = (const float4*)base;
  const int n4 = CPG * NN / 4;
  for (int idx = t; idx < n4; idx += 256) {
    float4 v = b4[idx];
    s += v.x + v.y + v.z + v.w;
    ss += v.x * v.x + v.y * v.y + v.z * v.z + v.w * v.w;
  }
  __shared__ float ls[256], lss[256];
  ls[t] = s; lss[t] = ss;
  __syncthreads();
  for (int o = 128; o > 0; o >>= 1) {
    if (t < o) { ls[t] += ls[t + o]; lss[t] += lss[t + o]; }
    __syncthreads();
  }
  if (t < CPG) {
    const float invn = 1.0f / (float)(CPG * NN);
    float mean = ls[0] * invn;
    float var = lss[0] * invn - mean * mean;
    float rstd = rsqrtf(var + EPSV);
    int c = g * CPG + t;
    float sc = rstd * gamma[c];
    scale[b * CC + c] = sc;
    shift[b * CC + c] = beta[c] - mean * sc;
  }
}

// ---------------------------------------------------------------------------
// fp32 [512x512] weight -> bf16 (row-major preserved)
// ---------------------------------------------------------------------------
__global__ __launch_bounds__(256) void cvt_bf16(const float* __restrict__ src,
                                                unsigned short* __restrict__ dst) {
  int i = blockIdx.x * 256 + threadIdx.x;
  float4 v = ((const float4*)src)[i];
  ushort4 o;
  o.x = f2bf(v.x); o.y = f2bf(v.y); o.z = f2bf(v.z); o.w = f2bf(v.w);
  ((ushort4*)dst)[i] = o;
}

// ---------------------------------------------------------------------------
// GN-apply + transpose: ht[b][n][c] (bf16) = x[b][c][n]*scale[b,c]+shift[b,c]
// 64x64 tiles through LDS; coalesced fp32 reads, coalesced bf16 writes.
// ---------------------------------------------------------------------------
__global__ __launch_bounds__(256) void gn_apply_t(
    const float* __restrict__ x, const float* __restrict__ scale,
    const float* __restrict__ shift, unsigned short* __restrict__ ht) {
  int b = blockIdx.z;
  int c0 = blockIdx.y * 64;
  int n0 = blockIdx.x * 64;
  const float* xb = x + ((size_t)b * CC + c0) * NN;
  __shared__ unsigned short tile[64][65];
  int t = threadIdx.x;
  int tn = t & 63, t4 = t >> 6;
#pragma unroll
  for (int r = 0; r < 16; ++r) {
    int c = r * 4 + t4;
    float sc = scale[b * CC + c0 + c];
    float sh = shift[b * CC + c0 + c];
    float v = xb[(size_t)c * NN + n0 + tn];
    tile[c][tn] = f2bf(v * sc + sh);
  }
  __syncthreads();
  unsigned short* hb = ht + (size_t)b * NN * CC;
#pragma unroll
  for (int r = 0; r < 16; ++r) {
    int n = r * 4 + t4;
    hb[(size_t)(n0 + n) * CC + c0 + tn] = tile[tn][n];
  }
}

// ---------------------------------------------------------------------------
// Generic TN bf16 MFMA GEMM (m97 structure):
//   C[m][n] = scale * sum_k A[m][k]*B[n][k]  (+bias, +resid)
// A: [M][K] bf16 pitch lda, B: [N][K] bf16 pitch ldb (K contiguous, 16B-aligned
// rows). BK=32. 256 threads = 4 waves in 2x2; wave tile (WM*16)x(WN*16).
// BIAS: 0 none, 1 per-row, 2 per-col.  OUTF32: fp32 store else bf16.
// ---------------------------------------------------------------------------
template <int BM, int BN, int WM, int WN, int BIAS, bool RESID, bool OUTF32>
__global__ __launch_bounds__(256) void gemm_tn(
    const unsigned short* __restrict__ A, int lda,
    const unsigned short* __restrict__ B, int ldb,
    void* __restrict__ Cout, int ldc, const float* __restrict__ bias,
    const float* __restrict__ resid, int K, float scale) {
  __shared__ unsigned short Al[BM * 32];
  __shared__ unsigned short Bl[BN * 32];
  const int m0 = blockIdx.y * BM;
  const int n0 = blockIdx.x * BN;
  const int t = threadIdx.x;
  const int wave = t >> 6, lane = t & 63;
  const int ln15 = lane & 15, quad = lane >> 4;
  const int wm0 = (wave >> 1) * (WM * 16);
  const int wn0 = (wave & 1) * (WN * 16);
  const int srow = lane >> 2;        // staging: row within 16-row chunk
  const int scol = (lane & 3) * 8;   // staging: element offset (8 bf16 = 16B)

  f32x4 acc[WM][WN];
#pragma unroll
  for (int i = 0; i < WM; ++i)
#pragma unroll
    for (int j = 0; j < WN; ++j) {
      acc[i][j][0] = 0.f; acc[i][j][1] = 0.f;
      acc[i][j][2] = 0.f; acc[i][j][3] = 0.f;
    }

  for (int k0 = 0; k0 < K; k0 += 32) {
#pragma unroll
    for (int r = wave; r < BM / 16; r += 4) {
      const unsigned short* gp =
          A + (size_t)(m0 + r * 16 + srow) * lda + k0 + scol;
      __builtin_amdgcn_global_load_lds(
          (const __attribute__((address_space(1))) void*)gp,
          (__attribute__((address_space(3))) void*)(Al + r * 16 * 32), 16, 0, 0);
    }
#pragma unroll
    for (int r = wave; r < BN / 16; r += 4) {
      const unsigned short* gp =
          B + (size_t)(n0 + r * 16 + srow) * ldb + k0 + scol;
      __builtin_amdgcn_global_load_lds(
          (const __attribute__((address_space(1))) void*)gp,
          (__attribute__((address_space(3))) void*)(Bl + r * 16 * 32), 16, 0, 0);
    }
    __syncthreads();
    bf16x8 af[WM], bf[WN];
#pragma unroll
    for (int i = 0; i < WM; ++i)
      af[i] = *(const bf16x8*)(Al + (wm0 + i * 16 + ln15) * 32 + quad * 8);
#pragma unroll
    for (int j = 0; j < WN; ++j)
      bf[j] = *(const bf16x8*)(Bl + (wn0 + j * 16 + ln15) * 32 + quad * 8);
#pragma unroll
    for (int i = 0; i < WM; ++i)
#pragma unroll
      for (int j = 0; j < WN; ++j)
        acc[i][j] = __builtin_amdgcn_mfma_f32_16x16x32_bf16(af[i], bf[j],
                                                            acc[i][j], 0, 0, 0);
    __syncthreads();
  }

#pragma unroll
  for (int i = 0; i < WM; ++i) {
#pragma unroll
    for (int j = 0; j < WN; ++j) {
      int col = n0 + wn0 + j * 16 + ln15;
      float bcol = (BIAS == 2) ? bias[col] : 0.f;
#pragma unroll
      for (int r = 0; r < 4; ++r) {
        int row = m0 + wm0 + i * 16 + quad * 4 + r;
        float v = acc[i][j][r] * scale;
        if (BIAS == 1) v += bias[row];
        if (BIAS == 2) v += bcol;
        if (RESID) v += resid[(size_t)row * ldc + col];
        if (OUTF32)
          ((float*)Cout)[(size_t)row * ldc + col] = v;
        else
          ((unsigned short*)Cout)[(size_t)row * ldc + col] = f2bf(v);
      }
    }
  }
}

// ---------------------------------------------------------------------------
// In-place bf16 row softmax: S row [4096] bf16; fp32 math internally.
// ---------------------------------------------------------------------------
__global__ __launch_bounds__(256) void softmax_bf16(unsigned short* __restrict__ S) {
  int i = blockIdx.x;
  uint4* row4 = (uint4*)(S + (size_t)i * NN);  // 512 x uint4 (8 bf16 each)
  int t = threadIdx.x;
  uint4 d[2];
  d[0] = row4[t];
  d[1] = row4[t + 256];
  float f[16];
#pragma unroll
  for (int h = 0; h < 2; ++h) {
    unsigned w[4] = {d[h].x, d[h].y, d[h].z, d[h].w};
#pragma unroll
    for (int q = 0; q < 4; ++q) {
      union { unsigned u; float f; } lo, hi;
      lo.u = w[q] << 16;
      hi.u = w[q] & 0xFFFF0000u;
      f[h * 8 + 2 * q] = lo.f;
      f[h * 8 + 2 * q + 1] = hi.f;
    }
  }
  float m = -1e30f;
#pragma unroll
  for (int e = 0; e < 16; ++e) m = fmaxf(m, f[e]);
  __shared__ float red[256];
  red[t] = m;
  __syncthreads();
  for (int o = 128; o > 0; o >>= 1) {
    if (t < o) red[t] = fmaxf(red[t], red[t + o]);
    __syncthreads();
  }
  m = red[0];
  __syncthreads();
  float s = 0.f;
#pragma unroll
  for (int e = 0; e < 16; ++e) {
    f[e] = __expf(f[e] - m);
    s += f[e];
  }
  red[t] = s;
  __syncthreads();
  for (int o = 128; o > 0; o >>= 1) {
    if (t < o) red[t] += red[t + o];
    __syncthreads();
  }
  float inv = 1.0f / red[0];
#pragma unroll
  for (int h = 0; h < 2; ++h) {
    unsigned w[4];
#pragma unroll
    for (int q = 0; q < 4; ++q) {
      unsigned short b0 = f2bf(f[h * 8 + 2 * q] * inv);
      unsigned short b1 = f2bf(f[h * 8 + 2 * q + 1] * inv);
      w[q] = ((unsigned)b1 << 16) | (unsigned)b0;
    }
    uint4 o4; o4.x = w[0]; o4.y = w[1]; o4.z = w[2]; o4.w = w[3];
    row4[t + h * 256] = o4;
  }
}

// ---------------------------------------------------------------------------
extern "C" void kernel_launch(void* const* d_in, const int* in_sizes, int n_in,
                              void* d_out, int out_size, void* d_ws,
                              size_t ws_size, hipStream_t stream) {
  const float* x = (const float*)d_in[0];
  const float* gamma = (const float*)d_in[1];
  const float* beta = (const float*)d_in[2];
  const float* Wq = (const float*)d_in[3];
  const float* bq = (const float*)d_in[4];
  const float* Wk = (const float*)d_in[5];
  const float* bk = (const float*)d_in[6];
  const float* Wv = (const float*)d_in[7];
  const float* bv = (const float*)d_in[8];
  const float* Wp = (const float*)d_in[9];
  const float* bp = (const float*)d_in[10];
  float* out = (float*)d_out;

  // workspace layout (~82 MiB, under the 96 MiB proven-safe budget)
  char* p = (char*)d_ws;
  unsigned short* ht = (unsigned short*)p; p += (size_t)BB * NN * CC * 2;  // 32M
  unsigned short* qt = (unsigned short*)p; p += (size_t)NN * CC * 2;      // 4M
  unsigned short* kt = (unsigned short*)p; p += (size_t)NN * CC * 2;      // 4M
  unsigned short* vv = (unsigned short*)p; p += (size_t)NN * CC * 2;      // 4M
  unsigned short* ot = (unsigned short*)p; p += (size_t)NN * CC * 2;      // 4M
  unsigned short* S  = (unsigned short*)p; p += (size_t)NN * NN * 2;      // 32M
  unsigned short* w16 = (unsigned short*)p; p += (size_t)4 * CC * CC * 2; // 2M
  unsigned short* wq16 = w16;
  unsigned short* wk16 = w16 + (size_t)CC * CC;
  unsigned short* wv16 = w16 + (size_t)2 * CC * CC;
  unsigned short* wp16 = w16 + (size_t)3 * CC * CC;
  float* scale = (float*)p; p += BB * CC * 4;
  float* shift = (float*)p;

  const float rs = 0.04419417382415922f;  // 1/sqrt(512)

  gn_stats<<<BB * GG, 256, 0, stream>>>(x, gamma, beta, scale, shift);
  cvt_bf16<<<256, 256, 0, stream>>>(Wq, wq16);
  cvt_bf16<<<256, 256, 0, stream>>>(Wk, wk16);
  cvt_bf16<<<256, 256, 0, stream>>>(Wv, wv16);
  cvt_bf16<<<256, 256, 0, stream>>>(Wp, wp16);
  gn_apply_t<<<dim3(NN / 64, CC / 64, BB), 256, 0, stream>>>(x, scale, shift,
                                                             ht);

  for (int b = 0; b < BB; ++b) {
    const unsigned short* htb = ht + (size_t)b * NN * CC;
    const float* xb = x + (size_t)b * CC * NN;
    // Q,K convs (transposed orientation): qt[n][m], M=4096, N=512
    gemm_tn<128, 64, 4, 2, 2, false, false>
        <<<dim3(CC / 64, NN / 128), 256, 0, stream>>>(
            htb, CC, wq16, CC, qt, CC, bq, nullptr, CC, 1.0f);
    gemm_tn<128, 64, 4, 2, 2, false, false>
        <<<dim3(CC / 64, NN / 128), 256, 0, stream>>>(
            htb, CC, wk16, CC, kt, CC, bk, nullptr, CC, 1.0f);
    // V conv (normal orientation): v[c][j], M=512, N=4096
    gemm_tn<64, 128, 2, 4, 1, false, false>
        <<<dim3(NN / 128, CC / 64), 256, 0, stream>>>(
            wv16, CC, htb, CC, vv, NN, bv, nullptr, CC, 1.0f);
    // S = (qt . kt^T) * rs : M=N=4096, K=512, bf16 out
    gemm_tn<128, 128, 4, 4, 0, false, false>
        <<<dim3(NN / 128, NN / 128), 256, 0, stream>>>(
            qt, CC, kt, CC, S, NN, nullptr, nullptr, CC, rs);
    softmax_bf16<<<NN, 256, 0, stream>>>(S);
    // ot[i][c] = sum_j P[i][j] v[c][j] : M=4096, N=512, K=4096
    gemm_tn<128, 64, 4, 2, 0, false, false>
        <<<dim3(CC / 64, NN / 128), 256, 0, stream>>>(
            S, NN, vv, NN, ot, CC, nullptr, nullptr, NN, 1.0f);
    // proj + bias + residual, fp32 out: M=512, N=4096, K=512
    gemm_tn<64, 128, 2, 4, 1, true, true>
        <<<dim3(NN / 128, CC / 64), 256, 0, stream>>>(
            wp16, CC, ot, CC, out + (size_t)b * CC * NN, NN, bp, xb, CC, 1.0f);
  }
}

// Round 4
// 1205.437 us; speedup vs baseline: 5.9757x; 1.1231x over previous
//
#include <hip/hip_runtime.h>
#include <math.h>

#define BB 8
#define CC 512
#define GG 32
#define CPG 16
#define NN 4096
#define EPSV 1e-5f

typedef __attribute__((ext_vector_type(8))) short bf16x8;
typedef __attribute__((ext_vector_type(4))) float f32x4;

__device__ __forceinline__ unsigned short f2bf(float f) {
  union { float f; unsigned u; } v;
  v.f = f;
  unsigned r = v.u + 0x7FFFu + ((v.u >> 16) & 1u);  // RNE
  return (unsigned short)(r >> 16);
}

// ---------------------------------------------------------------------------
// GroupNorm stats -> per (b,c) scale/shift (fp32)
// ---------------------------------------------------------------------------
__global__ __launch_bounds__(256) void gn_stats(
    const float* __restrict__ x, const float* __restrict__ gamma,
    const float* __restrict__ beta, float* __restrict__ scale,
    float* __restrict__ shift) {
  int bg = blockIdx.x;
  int b = bg / GG, g = bg % GG;
  const float* base = x + ((size_t)b * CC + (size_t)g * CPG) * NN;
  int t = threadIdx.x;
  float s = 0.f, ss = 0.f;
  const float4* b4 = (const float4*)base;
  const int n4 = CPG * NN / 4;
  for (int idx = t; idx < n4; idx += 256) {
    float4 v = b4[idx];
    s += v.x + v.y + v.z + v.w;
    ss += v.x * v.x + v.y * v.y + v.z * v.z + v.w * v.w;
  }
  __shared__ float ls[256], lss[256];
  ls[t] = s; lss[t] = ss;
  __syncthreads();
  for (int o = 128; o > 0; o >>= 1) {
    if (t < o) { ls[t] += ls[t + o]; lss[t] += lss[t + o]; }
    __syncthreads();
  }
  if (t < CPG) {
    const float invn = 1.0f / (float)(CPG * NN);
    float mean = ls[0] * invn;
    float var = lss[0] * invn - mean * mean;
    float rstd = rsqrtf(var + EPSV);
    int c = g * CPG + t;
    float sc = rstd * gamma[c];
    scale[b * CC + c] = sc;
    shift[b * CC + c] = beta[c] - mean * sc;
  }
}

// ---------------------------------------------------------------------------
// fp32 [512x512] weight -> bf16
// ---------------------------------------------------------------------------
__global__ __launch_bounds__(256) void cvt_bf16(const float* __restrict__ src,
                                                unsigned short* __restrict__ dst) {
  int i = blockIdx.x * 256 + threadIdx.x;
  float4 v = ((const float4*)src)[i];
  ushort4 o;
  o.x = f2bf(v.x); o.y = f2bf(v.y); o.z = f2bf(v.z); o.w = f2bf(v.w);
  ((ushort4*)dst)[i] = o;
}

// ---------------------------------------------------------------------------
// GN-apply + transpose for ONE batch: ht[n][c] = x[c][n]*scale[c]+shift[c]
// ---------------------------------------------------------------------------
__global__ __launch_bounds__(256) void gn_apply_t(
    const float* __restrict__ xb, const float* __restrict__ scb,
    const float* __restrict__ shb, unsigned short* __restrict__ ht) {
  int c0 = blockIdx.y * 64;
  int n0 = blockIdx.x * 64;
  __shared__ unsigned short tile[64][65];
  int t = threadIdx.x;
  int tn = t & 63, t4 = t >> 6;
#pragma unroll
  for (int r = 0; r < 16; ++r) {
    int c = r * 4 + t4;
    float sc = scb[c0 + c];
    float sh = shb[c0 + c];
    float v = xb[(size_t)(c0 + c) * NN + n0 + tn];
    tile[c][tn] = f2bf(v * sc + sh);
  }
  __syncthreads();
#pragma unroll
  for (int r = 0; r < 16; ++r) {
    int n = r * 4 + t4;
    ht[(size_t)(n0 + n) * CC + c0 + tn] = tile[tn][n];
  }
}

// ---------------------------------------------------------------------------
// bf16 transpose: vt[NN][CC] -> vv[CC][NN]
// ---------------------------------------------------------------------------
__global__ __launch_bounds__(256) void bf16_transpose(
    const unsigned short* __restrict__ vt, unsigned short* __restrict__ vv) {
  int j0 = blockIdx.x * 64;
  int c0 = blockIdx.y * 64;
  __shared__ unsigned short tile[64][65];
  int t = threadIdx.x;
  int tn = t & 63, t4 = t >> 6;
#pragma unroll
  for (int r = 0; r < 16; ++r) {
    int j = r * 4 + t4;
    tile[j][tn] = vt[(size_t)(j0 + j) * CC + c0 + tn];
  }
  __syncthreads();
#pragma unroll
  for (int r = 0; r < 16; ++r) {
    int c = r * 4 + t4;
    vv[(size_t)(c0 + c) * NN + j0 + tn] = tile[tn][c];
  }
}

// ---------------------------------------------------------------------------
// Fused QKV conv (one batch): A = ht [4096][512] K-major, Bx = W[cout][c].
//   qt[n][cout] = sum_c ht[n][c] Wq[cout][c] + bq[cout]   (same for k, vt)
// BM=128 (n), BN=64 (cout), BK=32; 4 waves 2x2; per-wave 4x2 frags x 3 mats.
// ---------------------------------------------------------------------------
__global__ __launch_bounds__(256) void qkv_conv(
    const unsigned short* __restrict__ A, const unsigned short* __restrict__ W0,
    const unsigned short* __restrict__ W1, const unsigned short* __restrict__ W2,
    const float* __restrict__ b0, const float* __restrict__ b1,
    const float* __restrict__ b2, unsigned short* __restrict__ C0,
    unsigned short* __restrict__ C1, unsigned short* __restrict__ C2) {
  __shared__ unsigned short Al[128 * 32];
  __shared__ unsigned short Bl0[64 * 32];
  __shared__ unsigned short Bl1[64 * 32];
  __shared__ unsigned short Bl2[64 * 32];
  const int m0 = blockIdx.y * 128;
  const int n0 = blockIdx.x * 64;
  const int t = threadIdx.x;
  const int wave = t >> 6, lane = t & 63;
  const int ln15 = lane & 15, quad = lane >> 4;
  const int wm0 = (wave >> 1) * 64;
  const int wn0 = (wave & 1) * 32;
  const int srow = lane >> 2;
  const int scol = (lane & 3) * 8;

  f32x4 acc0[4][2], acc1[4][2], acc2[4][2];
#pragma unroll
  for (int i = 0; i < 4; ++i)
#pragma unroll
    for (int j = 0; j < 2; ++j)
#pragma unroll
      for (int r = 0; r < 4; ++r) {
        acc0[i][j][r] = 0.f; acc1[i][j][r] = 0.f; acc2[i][j][r] = 0.f;
      }

  for (int k0 = 0; k0 < CC; k0 += 32) {
#pragma unroll
    for (int r = wave; r < 8; r += 4) {
      const unsigned short* gp = A + (size_t)(m0 + r * 16 + srow) * CC + k0 + scol;
      __builtin_amdgcn_global_load_lds(
          (const __attribute__((address_space(1))) void*)gp,
          (__attribute__((address_space(3))) void*)(Al + r * 16 * 32), 16, 0, 0);
    }
    {
      // 4 chunks of 16 rows across 3 B mats = 12 chunk-loads; waves 0..3 cover
      int r = wave;  // chunk for W0
      const unsigned short* gp = W0 + (size_t)(n0 + r * 16 + srow) * CC + k0 + scol;
      __builtin_amdgcn_global_load_lds(
          (const __attribute__((address_space(1))) void*)gp,
          (__attribute__((address_space(3))) void*)(Bl0 + r * 16 * 32), 16, 0, 0);
      gp = W1 + (size_t)(n0 + r * 16 + srow) * CC + k0 + scol;
      __builtin_amdgcn_global_load_lds(
          (const __attribute__((address_space(1))) void*)gp,
          (__attribute__((address_space(3))) void*)(Bl1 + r * 16 * 32), 16, 0, 0);
      gp = W2 + (size_t)(n0 + r * 16 + srow) * CC + k0 + scol;
      __builtin_amdgcn_global_load_lds(
          (const __attribute__((address_space(1))) void*)gp,
          (__attribute__((address_space(3))) void*)(Bl2 + r * 16 * 32), 16, 0, 0);
    }
    __syncthreads();
    bf16x8 af[4], bf0[2], bf1[2], bf2[2];
#pragma unroll
    for (int i = 0; i < 4; ++i)
      af[i] = *(const bf16x8*)(Al + (wm0 + i * 16 + ln15) * 32 + quad * 8);
#pragma unroll
    for (int j = 0; j < 2; ++j) {
      bf0[j] = *(const bf16x8*)(Bl0 + (wn0 + j * 16 + ln15) * 32 + quad * 8);
      bf1[j] = *(const bf16x8*)(Bl1 + (wn0 + j * 16 + ln15) * 32 + quad * 8);
      bf2[j] = *(const bf16x8*)(Bl2 + (wn0 + j * 16 + ln15) * 32 + quad * 8);
    }
#pragma unroll
    for (int i = 0; i < 4; ++i)
#pragma unroll
      for (int j = 0; j < 2; ++j) {
        acc0[i][j] = __builtin_amdgcn_mfma_f32_16x16x32_bf16(af[i], bf0[j], acc0[i][j], 0, 0, 0);
        acc1[i][j] = __builtin_amdgcn_mfma_f32_16x16x32_bf16(af[i], bf1[j], acc1[i][j], 0, 0, 0);
        acc2[i][j] = __builtin_amdgcn_mfma_f32_16x16x32_bf16(af[i], bf2[j], acc2[i][j], 0, 0, 0);
      }
    __syncthreads();
  }
#pragma unroll
  for (int i = 0; i < 4; ++i)
#pragma unroll
    for (int j = 0; j < 2; ++j) {
      int col = n0 + wn0 + j * 16 + ln15;
      float c0b = b0[col], c1b = b1[col], c2b = b2[col];
#pragma unroll
      for (int r = 0; r < 4; ++r) {
        int row = m0 + wm0 + i * 16 + quad * 4 + r;
        size_t off = (size_t)row * CC + col;
        C0[off] = f2bf(acc0[i][j][r] + c0b);
        C1[off] = f2bf(acc1[i][j][r] + c1b);
        C2[off] = f2bf(acc2[i][j][r] + c2b);
      }
    }
}

// ---------------------------------------------------------------------------
// Generic TN bf16 MFMA GEMM:
//   C[m][n] = scale * sum_k A[m][k]*B[n][k]  (+bias, +resid)
// PART: split-K over blockIdx.z (K = chunk size), fp32 partial out per plane.
// BIAS: 0 none, 1 per-row, 2 per-col.  OUTF32: fp32 store else bf16.
// ---------------------------------------------------------------------------
template <int BM, int BN, int WM, int WN, int BIAS, bool RESID, bool OUTF32,
          bool PART>
__global__ __launch_bounds__(256) void gemm_tn(
    const unsigned short* __restrict__ A, int lda,
    const unsigned short* __restrict__ B, int ldb,
    void* __restrict__ Cout, int ldc, const float* __restrict__ bias,
    const float* __restrict__ resid, int K, float scale, int plane) {
  __shared__ unsigned short Al[BM * 32];
  __shared__ unsigned short Bl[BN * 32];
  const int m0 = blockIdx.y * BM;
  const int n0 = blockIdx.x * BN;
  const size_t koff = PART ? (size_t)blockIdx.z * K : 0;
  const int t = threadIdx.x;
  const int wave = t >> 6, lane = t & 63;
  const int ln15 = lane & 15, quad = lane >> 4;
  const int wm0 = (wave >> 1) * (WM * 16);
  const int wn0 = (wave & 1) * (WN * 16);
  const int srow = lane >> 2;
  const int scol = (lane & 3) * 8;

  f32x4 acc[WM][WN];
#pragma unroll
  for (int i = 0; i < WM; ++i)
#pragma unroll
    for (int j = 0; j < WN; ++j) {
      acc[i][j][0] = 0.f; acc[i][j][1] = 0.f;
      acc[i][j][2] = 0.f; acc[i][j][3] = 0.f;
    }

  for (int k0 = 0; k0 < K; k0 += 32) {
#pragma unroll
    for (int r = wave; r < BM / 16; r += 4) {
      const unsigned short* gp =
          A + (size_t)(m0 + r * 16 + srow) * lda + koff + k0 + scol;
      __builtin_amdgcn_global_load_lds(
          (const __attribute__((address_space(1))) void*)gp,
          (__attribute__((address_space(3))) void*)(Al + r * 16 * 32), 16, 0, 0);
    }
#pragma unroll
    for (int r = wave; r < BN / 16; r += 4) {
      const unsigned short* gp =
          B + (size_t)(n0 + r * 16 + srow) * ldb + koff + k0 + scol;
      __builtin_amdgcn_global_load_lds(
          (const __attribute__((address_space(1))) void*)gp,
          (__attribute__((address_space(3))) void*)(Bl + r * 16 * 32), 16, 0, 0);
    }
    __syncthreads();
    bf16x8 af[WM], bfr[WN];
#pragma unroll
    for (int i = 0; i < WM; ++i)
      af[i] = *(const bf16x8*)(Al + (wm0 + i * 16 + ln15) * 32 + quad * 8);
#pragma unroll
    for (int j = 0; j < WN; ++j)
      bfr[j] = *(const bf16x8*)(Bl + (wn0 + j * 16 + ln15) * 32 + quad * 8);
#pragma unroll
    for (int i = 0; i < WM; ++i)
#pragma unroll
      for (int j = 0; j < WN; ++j)
        acc[i][j] = __builtin_amdgcn_mfma_f32_16x16x32_bf16(af[i], bfr[j],
                                                            acc[i][j], 0, 0, 0);
    __syncthreads();
  }

#pragma unroll
  for (int i = 0; i < WM; ++i) {
#pragma unroll
    for (int j = 0; j < WN; ++j) {
      int col = n0 + wn0 + j * 16 + ln15;
      float bcol = (BIAS == 2) ? bias[col] : 0.f;
#pragma unroll
      for (int r = 0; r < 4; ++r) {
        int row = m0 + wm0 + i * 16 + quad * 4 + r;
        float v = acc[i][j][r] * scale;
        if (BIAS == 1) v += bias[row];
        if (BIAS == 2) v += bcol;
        if (RESID) v += resid[(size_t)row * ldc + col];
        if (PART)
          ((float*)Cout)[(size_t)blockIdx.z * plane + (size_t)row * ldc + col] = v;
        else if (OUTF32)
          ((float*)Cout)[(size_t)row * ldc + col] = v;
        else
          ((unsigned short*)Cout)[(size_t)row * ldc + col] = f2bf(v);
      }
    }
  }
}

// ---------------------------------------------------------------------------
// Split-K reduce: ot[i][c] (bf16) = sum over 4 fp32 planes
// ---------------------------------------------------------------------------
__global__ __launch_bounds__(256) void reduce4(
    const float* __restrict__ part, unsigned short* __restrict__ ot) {
  const size_t plane = (size_t)NN * CC;
  size_t e = ((size_t)blockIdx.x * 256 + threadIdx.x) * 4;
  float4 a = *(const float4*)(part + e);
  float4 b = *(const float4*)(part + plane + e);
  float4 c = *(const float4*)(part + 2 * plane + e);
  float4 d = *(const float4*)(part + 3 * plane + e);
  ushort4 o;
  o.x = f2bf(a.x + b.x + c.x + d.x);
  o.y = f2bf(a.y + b.y + c.y + d.y);
  o.z = f2bf(a.z + b.z + c.z + d.z);
  o.w = f2bf(a.w + b.w + c.w + d.w);
  *(ushort4*)(ot + e) = o;
}

// ---------------------------------------------------------------------------
// In-place bf16 row softmax (fp32 math)
// ---------------------------------------------------------------------------
__global__ __launch_bounds__(256) void softmax_bf16(unsigned short* __restrict__ S) {
  int i = blockIdx.x;
  uint4* row4 = (uint4*)(S + (size_t)i * NN);
  int t = threadIdx.x;
  uint4 d[2];
  d[0] = row4[t];
  d[1] = row4[t + 256];
  float f[16];
#pragma unroll
  for (int h = 0; h < 2; ++h) {
    unsigned w[4] = {d[h].x, d[h].y, d[h].z, d[h].w};
#pragma unroll
    for (int q = 0; q < 4; ++q) {
      union { unsigned u; float f; } lo, hi;
      lo.u = w[q] << 16;
      hi.u = w[q] & 0xFFFF0000u;
      f[h * 8 + 2 * q] = lo.f;
      f[h * 8 + 2 * q + 1] = hi.f;
    }
  }
  float m = -1e30f;
#pragma unroll
  for (int e = 0; e < 16; ++e) m = fmaxf(m, f[e]);
  __shared__ float red[256];
  red[t] = m;
  __syncthreads();
  for (int o = 128; o > 0; o >>= 1) {
    if (t < o) red[t] = fmaxf(red[t], red[t + o]);
    __syncthreads();
  }
  m = red[0];
  __syncthreads();
  float s = 0.f;
#pragma unroll
  for (int e = 0; e < 16; ++e) {
    f[e] = __expf(f[e] - m);
    s += f[e];
  }
  red[t] = s;
  __syncthreads();
  for (int o = 128; o > 0; o >>= 1) {
    if (t < o) red[t] += red[t + o];
    __syncthreads();
  }
  float inv = 1.0f / red[0];
#pragma unroll
  for (int h = 0; h < 2; ++h) {
    unsigned w[4];
#pragma unroll
    for (int q = 0; q < 4; ++q) {
      unsigned short b0 = f2bf(f[h * 8 + 2 * q] * inv);
      unsigned short b1 = f2bf(f[h * 8 + 2 * q + 1] * inv);
      w[q] = ((unsigned)b1 << 16) | (unsigned)b0;
    }
    uint4 o4; o4.x = w[0]; o4.y = w[1]; o4.z = w[2]; o4.w = w[3];
    row4[t + h * 256] = o4;
  }
}

// ---------------------------------------------------------------------------
extern "C" void kernel_launch(void* const* d_in, const int* in_sizes, int n_in,
                              void* d_out, int out_size, void* d_ws,
                              size_t ws_size, hipStream_t stream) {
  const float* x = (const float*)d_in[0];
  const float* gamma = (const float*)d_in[1];
  const float* beta = (const float*)d_in[2];
  const float* Wq = (const float*)d_in[3];
  const float* bq = (const float*)d_in[4];
  const float* Wk = (const float*)d_in[5];
  const float* bk = (const float*)d_in[6];
  const float* Wv = (const float*)d_in[7];
  const float* bv = (const float*)d_in[8];
  const float* Wp = (const float*)d_in[9];
  const float* bp = (const float*)d_in[10];
  float* out = (float*)d_out;

  // workspace (~90 MiB, under the 96 MiB proven-safe budget)
  char* p = (char*)d_ws;
  const size_t CN2 = (size_t)NN * CC * 2;                   // 4 MiB
  unsigned short* ht = (unsigned short*)p; p += CN2;
  unsigned short* qt = (unsigned short*)p; p += CN2;
  unsigned short* kt = (unsigned short*)p; p += CN2;
  unsigned short* vt = (unsigned short*)p; p += CN2;
  unsigned short* vv = (unsigned short*)p; p += CN2;
  unsigned short* ot = (unsigned short*)p; p += CN2;
  unsigned short* S  = (unsigned short*)p; p += (size_t)NN * NN * 2;  // 32 MiB
  float* part = (float*)p; p += (size_t)4 * NN * CC * 4;              // 32 MiB
  unsigned short* w16 = (unsigned short*)p; p += (size_t)4 * CC * CC * 2;
  unsigned short* wq16 = w16;
  unsigned short* wk16 = w16 + (size_t)CC * CC;
  unsigned short* wv16 = w16 + (size_t)2 * CC * CC;
  unsigned short* wp16 = w16 + (size_t)3 * CC * CC;
  float* scale = (float*)p; p += BB * CC * 4;
  float* shift = (float*)p;

  const float rs = 0.04419417382415922f;  // 1/sqrt(512)

  gn_stats<<<BB * GG, 256, 0, stream>>>(x, gamma, beta, scale, shift);
  cvt_bf16<<<256, 256, 0, stream>>>(Wq, wq16);
  cvt_bf16<<<256, 256, 0, stream>>>(Wk, wk16);
  cvt_bf16<<<256, 256, 0, stream>>>(Wv, wv16);
  cvt_bf16<<<256, 256, 0, stream>>>(Wp, wp16);

  for (int b = 0; b < BB; ++b) {
    const float* xb = x + (size_t)b * CC * NN;
    // GN apply + transpose -> ht[n][c]
    gn_apply_t<<<dim3(NN / 64, CC / 64), 256, 0, stream>>>(
        xb, scale + b * CC, shift + b * CC, ht);
    // fused QKV conv -> qt[n][m], kt[n][m], vt[n][m]
    qkv_conv<<<dim3(CC / 64, NN / 128), 256, 0, stream>>>(
        ht, wq16, wk16, wv16, bq, bk, bv, qt, kt, vt);
    // vt[j][c] -> vv[c][j]
    bf16_transpose<<<dim3(NN / 64, CC / 64), 256, 0, stream>>>(vt, vv);
    // S = (qt . kt^T) * rs : M=N=4096, K=512
    gemm_tn<128, 128, 4, 4, 0, false, false, false>
        <<<dim3(NN / 128, NN / 128), 256, 0, stream>>>(
            qt, CC, kt, CC, S, NN, nullptr, nullptr, CC, rs, 0);
    softmax_bf16<<<NN, 256, 0, stream>>>(S);
    // PV split-K=4: part[z][i][c] = sum_{j in chunk z} P[i][j] v[c][j]
    gemm_tn<128, 64, 4, 2, 0, false, false, true>
        <<<dim3(CC / 64, NN / 128, 4), 256, 0, stream>>>(
            S, NN, vv, NN, part, CC, nullptr, nullptr, NN / 4, 1.0f, NN * CC);
    reduce4<<<(NN * CC / 4) / 256, 256, 0, stream>>>(part, ot);
    // proj + bias + residual, fp32 out: M=512(co), N=4096, K=512
    gemm_tn<64, 64, 2, 2, 1, true, true, false>
        <<<dim3(NN / 64, CC / 64), 256, 0, stream>>>(
            wp16, CC, ot, CC, out + (size_t)b * CC * NN, NN, bp, xb, CC, 1.0f, 0);
  }
}

// Round 5
// 1112.066 us; speedup vs baseline: 6.4775x; 1.0840x over previous
//
#include <hip/hip_runtime.h>
#include <math.h>

#define BB 8
#define CC 512
#define GG 32
#define CPG 16
#define NN 4096
#define EPSV 1e-5f

typedef __attribute__((ext_vector_type(8))) short bf16x8;
typedef __attribute__((ext_vector_type(4))) float f32x4;

__device__ __forceinline__ unsigned short f2bf(float f) {
  union { float f; unsigned u; } v;
  v.f = f;
  unsigned r = v.u + 0x7FFFu + ((v.u >> 16) & 1u);  // RNE
  return (unsigned short)(r >> 16);
}

// ---------------------------------------------------------------------------
// GroupNorm stats -> per (b,c) scale/shift (fp32)
// ---------------------------------------------------------------------------
__global__ __launch_bounds__(256) void gn_stats(
    const float* __restrict__ x, const float* __restrict__ gamma,
    const float* __restrict__ beta, float* __restrict__ scale,
    float* __restrict__ shift) {
  int bg = blockIdx.x;
  int b = bg / GG, g = bg % GG;
  const float* base = x + ((size_t)b * CC + (size_t)g * CPG) * NN;
  int t = threadIdx.x;
  float s = 0.f, ss = 0.f;
  const float4* b4 = (const float4*)base;
  const int n4 = CPG * NN / 4;
  for (int idx = t; idx < n4; idx += 256) {
    float4 v = b4[idx];
    s += v.x + v.y + v.z + v.w;
    ss += v.x * v.x + v.y * v.y + v.z * v.z + v.w * v.w;
  }
  __shared__ float ls[256], lss[256];
  ls[t] = s; lss[t] = ss;
  __syncthreads();
  for (int o = 128; o > 0; o >>= 1) {
    if (t < o) { ls[t] += ls[t + o]; lss[t] += lss[t + o]; }
    __syncthreads();
  }
  if (t < CPG) {
    const float invn = 1.0f / (float)(CPG * NN);
    float mean = ls[0] * invn;
    float var = lss[0] * invn - mean * mean;
    float rstd = rsqrtf(var + EPSV);
    int c = g * CPG + t;
    float sc = rstd * gamma[c];
    scale[b * CC + c] = sc;
    shift[b * CC + c] = beta[c] - mean * sc;
  }
}

// ---------------------------------------------------------------------------
// fp32 [512x512] weight -> bf16
// ---------------------------------------------------------------------------
__global__ __launch_bounds__(256) void cvt_bf16(const float* __restrict__ src,
                                                unsigned short* __restrict__ dst) {
  int i = blockIdx.x * 256 + threadIdx.x;
  float4 v = ((const float4*)src)[i];
  ushort4 o;
  o.x = f2bf(v.x); o.y = f2bf(v.y); o.z = f2bf(v.z); o.w = f2bf(v.w);
  ((ushort4*)dst)[i] = o;
}

// ---------------------------------------------------------------------------
// GN-apply + transpose for ONE batch: ht[n][c] = x[c][n]*scale[c]+shift[c]
// ---------------------------------------------------------------------------
__global__ __launch_bounds__(256) void gn_apply_t(
    const float* __restrict__ xb, const float* __restrict__ scb,
    const float* __restrict__ shb, unsigned short* __restrict__ ht) {
  int c0 = blockIdx.y * 64;
  int n0 = blockIdx.x * 64;
  __shared__ unsigned short tile[64][65];
  int t = threadIdx.x;
  int tn = t & 63, t4 = t >> 6;
#pragma unroll
  for (int r = 0; r < 16; ++r) {
    int c = r * 4 + t4;
    float sc = scb[c0 + c];
    float sh = shb[c0 + c];
    float v = xb[(size_t)(c0 + c) * NN + n0 + tn];
    tile[c][tn] = f2bf(v * sc + sh);
  }
  __syncthreads();
#pragma unroll
  for (int r = 0; r < 16; ++r) {
    int n = r * 4 + t4;
    ht[(size_t)(n0 + n) * CC + c0 + tn] = tile[tn][n];
  }
}

// ---------------------------------------------------------------------------
// Fused QKV conv (one batch): A = ht [4096][512] K-major, Bx = W[cout][c].
//   qt[n][cout], kt[n][cout]  (row-major n)  ;  V written TRANSPOSED into
//   vv[cout][n] directly from the C-layout fragments (4 consecutive spatial
//   rows per lane -> ushort4 stores).
// ---------------------------------------------------------------------------
__global__ __launch_bounds__(256) void qkv_conv(
    const unsigned short* __restrict__ A, const unsigned short* __restrict__ W0,
    const unsigned short* __restrict__ W1, const unsigned short* __restrict__ W2,
    const float* __restrict__ b0, const float* __restrict__ b1,
    const float* __restrict__ b2, unsigned short* __restrict__ C0,
    unsigned short* __restrict__ C1, unsigned short* __restrict__ vv) {
  __shared__ unsigned short Al[128 * 32];
  __shared__ unsigned short Bl0[64 * 32];
  __shared__ unsigned short Bl1[64 * 32];
  __shared__ unsigned short Bl2[64 * 32];
  const int m0 = blockIdx.y * 128;
  const int n0 = blockIdx.x * 64;
  const int t = threadIdx.x;
  const int wave = t >> 6, lane = t & 63;
  const int ln15 = lane & 15, quad = lane >> 4;
  const int wm0 = (wave >> 1) * 64;
  const int wn0 = (wave & 1) * 32;
  const int srow = lane >> 2;
  const int scol = (lane & 3) * 8;

  f32x4 acc0[4][2], acc1[4][2], acc2[4][2];
#pragma unroll
  for (int i = 0; i < 4; ++i)
#pragma unroll
    for (int j = 0; j < 2; ++j)
#pragma unroll
      for (int r = 0; r < 4; ++r) {
        acc0[i][j][r] = 0.f; acc1[i][j][r] = 0.f; acc2[i][j][r] = 0.f;
      }

  for (int k0 = 0; k0 < CC; k0 += 32) {
#pragma unroll
    for (int r = wave; r < 8; r += 4) {
      const unsigned short* gp = A + (size_t)(m0 + r * 16 + srow) * CC + k0 + scol;
      __builtin_amdgcn_global_load_lds(
          (const __attribute__((address_space(1))) void*)gp,
          (__attribute__((address_space(3))) void*)(Al + r * 16 * 32), 16, 0, 0);
    }
    {
      int r = wave;
      const unsigned short* gp = W0 + (size_t)(n0 + r * 16 + srow) * CC + k0 + scol;
      __builtin_amdgcn_global_load_lds(
          (const __attribute__((address_space(1))) void*)gp,
          (__attribute__((address_space(3))) void*)(Bl0 + r * 16 * 32), 16, 0, 0);
      gp = W1 + (size_t)(n0 + r * 16 + srow) * CC + k0 + scol;
      __builtin_amdgcn_global_load_lds(
          (const __attribute__((address_space(1))) void*)gp,
          (__attribute__((address_space(3))) void*)(Bl1 + r * 16 * 32), 16, 0, 0);
      gp = W2 + (size_t)(n0 + r * 16 + srow) * CC + k0 + scol;
      __builtin_amdgcn_global_load_lds(
          (const __attribute__((address_space(1))) void*)gp,
          (__attribute__((address_space(3))) void*)(Bl2 + r * 16 * 32), 16, 0, 0);
    }
    __syncthreads();
    bf16x8 af[4], bf0[2], bf1[2], bf2[2];
#pragma unroll
    for (int i = 0; i < 4; ++i)
      af[i] = *(const bf16x8*)(Al + (wm0 + i * 16 + ln15) * 32 + quad * 8);
#pragma unroll
    for (int j = 0; j < 2; ++j) {
      bf0[j] = *(const bf16x8*)(Bl0 + (wn0 + j * 16 + ln15) * 32 + quad * 8);
      bf1[j] = *(const bf16x8*)(Bl1 + (wn0 + j * 16 + ln15) * 32 + quad * 8);
      bf2[j] = *(const bf16x8*)(Bl2 + (wn0 + j * 16 + ln15) * 32 + quad * 8);
    }
#pragma unroll
    for (int i = 0; i < 4; ++i)
#pragma unroll
      for (int j = 0; j < 2; ++j) {
        acc0[i][j] = __builtin_amdgcn_mfma_f32_16x16x32_bf16(af[i], bf0[j], acc0[i][j], 0, 0, 0);
        acc1[i][j] = __builtin_amdgcn_mfma_f32_16x16x32_bf16(af[i], bf1[j], acc1[i][j], 0, 0, 0);
        acc2[i][j] = __builtin_amdgcn_mfma_f32_16x16x32_bf16(af[i], bf2[j], acc2[i][j], 0, 0, 0);
      }
    __syncthreads();
  }
#pragma unroll
  for (int i = 0; i < 4; ++i)
#pragma unroll
    for (int j = 0; j < 2; ++j) {
      int col = n0 + wn0 + j * 16 + ln15;
      float c0b = b0[col], c1b = b1[col], c2b = b2[col];
      int row0 = m0 + wm0 + i * 16 + quad * 4;
#pragma unroll
      for (int r = 0; r < 4; ++r) {
        size_t off = (size_t)(row0 + r) * CC + col;
        C0[off] = f2bf(acc0[i][j][r] + c0b);
        C1[off] = f2bf(acc1[i][j][r] + c1b);
      }
      // V transposed store: vv[c][n], 4 consecutive n per lane -> ushort4
      ushort4 pk;
      pk.x = f2bf(acc2[i][j][0] + c2b);
      pk.y = f2bf(acc2[i][j][1] + c2b);
      pk.z = f2bf(acc2[i][j][2] + c2b);
      pk.w = f2bf(acc2[i][j][3] + c2b);
      *(ushort4*)(vv + (size_t)col * NN + row0) = pk;
    }
}

// ---------------------------------------------------------------------------
// Generic TN bf16 MFMA GEMM:
//   C[m][n] = scale * sum_k A[m][k]*B[n][k]  (+bias, +resid)
// WX: waves along n (4 waves arranged (4/WX) x WX).
// PART: split-K over blockIdx.z (K = chunk), bf16 partial planes.
// BIAS: 0 none, 1 per-row(col idx), 2 per-col.  OUTF32: fp32 store else bf16.
// ---------------------------------------------------------------------------
template <int BM, int BN, int WM, int WN, int WX, int BIAS, bool RESID,
          bool OUTF32, bool PART>
__global__ __launch_bounds__(256) void gemm_tn(
    const unsigned short* __restrict__ A, int lda,
    const unsigned short* __restrict__ B, int ldb,
    void* __restrict__ Cout, int ldc, const float* __restrict__ bias,
    const float* __restrict__ resid, int K, float scale, int plane) {
  __shared__ unsigned short Al[BM * 32];
  __shared__ unsigned short Bl[BN * 32];
  const int m0 = blockIdx.y * BM;
  const int n0 = blockIdx.x * BN;
  const size_t koff = PART ? (size_t)blockIdx.z * K : 0;
  const int t = threadIdx.x;
  const int wave = t >> 6, lane = t & 63;
  const int ln15 = lane & 15, quad = lane >> 4;
  const int wm0 = (wave / WX) * (WM * 16);
  const int wn0 = (wave % WX) * (WN * 16);
  const int srow = lane >> 2;
  const int scol = (lane & 3) * 8;

  f32x4 acc[WM][WN];
#pragma unroll
  for (int i = 0; i < WM; ++i)
#pragma unroll
    for (int j = 0; j < WN; ++j) {
      acc[i][j][0] = 0.f; acc[i][j][1] = 0.f;
      acc[i][j][2] = 0.f; acc[i][j][3] = 0.f;
    }

  for (int k0 = 0; k0 < K; k0 += 32) {
#pragma unroll
    for (int r = wave; r < BM / 16; r += 4) {
      const unsigned short* gp =
          A + (size_t)(m0 + r * 16 + srow) * lda + koff + k0 + scol;
      __builtin_amdgcn_global_load_lds(
          (const __attribute__((address_space(1))) void*)gp,
          (__attribute__((address_space(3))) void*)(Al + r * 16 * 32), 16, 0, 0);
    }
#pragma unroll
    for (int r = wave; r < BN / 16; r += 4) {
      const unsigned short* gp =
          B + (size_t)(n0 + r * 16 + srow) * ldb + koff + k0 + scol;
      __builtin_amdgcn_global_load_lds(
          (const __attribute__((address_space(1))) void*)gp,
          (__attribute__((address_space(3))) void*)(Bl + r * 16 * 32), 16, 0, 0);
    }
    __syncthreads();
    bf16x8 af[WM], bfr[WN];
#pragma unroll
    for (int i = 0; i < WM; ++i)
      af[i] = *(const bf16x8*)(Al + (wm0 + i * 16 + ln15) * 32 + quad * 8);
#pragma unroll
    for (int j = 0; j < WN; ++j)
      bfr[j] = *(const bf16x8*)(Bl + (wn0 + j * 16 + ln15) * 32 + quad * 8);
#pragma unroll
    for (int i = 0; i < WM; ++i)
#pragma unroll
      for (int j = 0; j < WN; ++j)
        acc[i][j] = __builtin_amdgcn_mfma_f32_16x16x32_bf16(af[i], bfr[j],
                                                            acc[i][j], 0, 0, 0);
    __syncthreads();
  }

#pragma unroll
  for (int i = 0; i < WM; ++i) {
#pragma unroll
    for (int j = 0; j < WN; ++j) {
      int col = n0 + wn0 + j * 16 + ln15;
      float bcol = (BIAS == 2) ? bias[col] : 0.f;
#pragma unroll
      for (int r = 0; r < 4; ++r) {
        int row = m0 + wm0 + i * 16 + quad * 4 + r;
        float v = acc[i][j][r] * scale;
        if (BIAS == 1) v += bias[row];
        if (BIAS == 2) v += bcol;
        if (RESID) v += resid[(size_t)row * ldc + col];
        if (PART)
          ((unsigned short*)Cout)[(size_t)blockIdx.z * plane +
                                  (size_t)row * ldc + col] = f2bf(v);
        else if (OUTF32)
          ((float*)Cout)[(size_t)row * ldc + col] = v;
        else
          ((unsigned short*)Cout)[(size_t)row * ldc + col] = f2bf(v);
      }
    }
  }
}

// ---------------------------------------------------------------------------
// Split-K reduce: ot (bf16) = sum over 8 bf16 planes (fp32 accumulate)
// ---------------------------------------------------------------------------
__global__ __launch_bounds__(256) void reduce8(
    const unsigned short* __restrict__ part, unsigned short* __restrict__ ot) {
  const size_t plane = (size_t)NN * CC;
  size_t e = ((size_t)blockIdx.x * 256 + threadIdx.x) * 8;
  float acc[8] = {};
#pragma unroll
  for (int p = 0; p < 8; ++p) {
    uint4 d = *(const uint4*)(part + p * plane + e);
    unsigned w[4] = {d.x, d.y, d.z, d.w};
#pragma unroll
    for (int q = 0; q < 4; ++q) {
      union { unsigned u; float f; } lo, hi;
      lo.u = w[q] << 16;
      hi.u = w[q] & 0xFFFF0000u;
      acc[2 * q] += lo.f;
      acc[2 * q + 1] += hi.f;
    }
  }
  unsigned o[4];
#pragma unroll
  for (int q = 0; q < 4; ++q) {
    unsigned short b0 = f2bf(acc[2 * q]);
    unsigned short b1 = f2bf(acc[2 * q + 1]);
    o[q] = ((unsigned)b1 << 16) | (unsigned)b0;
  }
  uint4 o4; o4.x = o[0]; o4.y = o[1]; o4.z = o[2]; o4.w = o[3];
  *(uint4*)(ot + e) = o4;
}

// ---------------------------------------------------------------------------
// In-place bf16 row softmax (fp32 math)
// ---------------------------------------------------------------------------
__global__ __launch_bounds__(256) void softmax_bf16(unsigned short* __restrict__ S) {
  int i = blockIdx.x;
  uint4* row4 = (uint4*)(S + (size_t)i * NN);
  int t = threadIdx.x;
  uint4 d[2];
  d[0] = row4[t];
  d[1] = row4[t + 256];
  float f[16];
#pragma unroll
  for (int h = 0; h < 2; ++h) {
    unsigned w[4] = {d[h].x, d[h].y, d[h].z, d[h].w};
#pragma unroll
    for (int q = 0; q < 4; ++q) {
      union { unsigned u; float f; } lo, hi;
      lo.u = w[q] << 16;
      hi.u = w[q] & 0xFFFF0000u;
      f[h * 8 + 2 * q] = lo.f;
      f[h * 8 + 2 * q + 1] = hi.f;
    }
  }
  float m = -1e30f;
#pragma unroll
  for (int e = 0; e < 16; ++e) m = fmaxf(m, f[e]);
  __shared__ float red[256];
  red[t] = m;
  __syncthreads();
  for (int o = 128; o > 0; o >>= 1) {
    if (t < o) red[t] = fmaxf(red[t], red[t + o]);
    __syncthreads();
  }
  m = red[0];
  __syncthreads();
  float s = 0.f;
#pragma unroll
  for (int e = 0; e < 16; ++e) {
    f[e] = __expf(f[e] - m);
    s += f[e];
  }
  red[t] = s;
  __syncthreads();
  for (int o = 128; o > 0; o >>= 1) {
    if (t < o) red[t] += red[t + o];
    __syncthreads();
  }
  float inv = 1.0f / red[0];
#pragma unroll
  for (int h = 0; h < 2; ++h) {
    unsigned w[4];
#pragma unroll
    for (int q = 0; q < 4; ++q) {
      unsigned short b0 = f2bf(f[h * 8 + 2 * q] * inv);
      unsigned short b1 = f2bf(f[h * 8 + 2 * q + 1] * inv);
      w[q] = ((unsigned)b1 << 16) | (unsigned)b0;
    }
    uint4 o4; o4.x = w[0]; o4.y = w[1]; o4.z = w[2]; o4.w = w[3];
    row4[t + h * 256] = o4;
  }
}

// ---------------------------------------------------------------------------
extern "C" void kernel_launch(void* const* d_in, const int* in_sizes, int n_in,
                              void* d_out, int out_size, void* d_ws,
                              size_t ws_size, hipStream_t stream) {
  const float* x = (const float*)d_in[0];
  const float* gamma = (const float*)d_in[1];
  const float* beta = (const float*)d_in[2];
  const float* Wq = (const float*)d_in[3];
  const float* bq = (const float*)d_in[4];
  const float* Wk = (const float*)d_in[5];
  const float* bk = (const float*)d_in[6];
  const float* Wv = (const float*)d_in[7];
  const float* bv = (const float*)d_in[8];
  const float* Wp = (const float*)d_in[9];
  const float* bp = (const float*)d_in[10];
  float* out = (float*)d_out;

  // workspace (~86 MiB, under the 96 MiB proven-safe budget)
  char* p = (char*)d_ws;
  const size_t CN2 = (size_t)NN * CC * 2;                   // 4 MiB
  unsigned short* ht = (unsigned short*)p; p += CN2;
  unsigned short* qt = (unsigned short*)p; p += CN2;
  unsigned short* kt = (unsigned short*)p; p += CN2;
  unsigned short* vv = (unsigned short*)p; p += CN2;
  unsigned short* ot = (unsigned short*)p; p += CN2;
  unsigned short* S  = (unsigned short*)p; p += (size_t)NN * NN * 2;   // 32 MiB
  unsigned short* part = (unsigned short*)p; p += (size_t)8 * NN * CC * 2; // 32
  unsigned short* w16 = (unsigned short*)p; p += (size_t)4 * CC * CC * 2;
  unsigned short* wq16 = w16;
  unsigned short* wk16 = w16 + (size_t)CC * CC;
  unsigned short* wv16 = w16 + (size_t)2 * CC * CC;
  unsigned short* wp16 = w16 + (size_t)3 * CC * CC;
  float* scale = (float*)p; p += BB * CC * 4;
  float* shift = (float*)p;

  const float rs = 0.04419417382415922f;  // 1/sqrt(512)

  gn_stats<<<BB * GG, 256, 0, stream>>>(x, gamma, beta, scale, shift);
  cvt_bf16<<<256, 256, 0, stream>>>(Wq, wq16);
  cvt_bf16<<<256, 256, 0, stream>>>(Wk, wk16);
  cvt_bf16<<<256, 256, 0, stream>>>(Wv, wv16);
  cvt_bf16<<<256, 256, 0, stream>>>(Wp, wp16);

  for (int b = 0; b < BB; ++b) {
    const float* xb = x + (size_t)b * CC * NN;
    // GN apply + transpose -> ht[n][c]
    gn_apply_t<<<dim3(NN / 64, CC / 64), 256, 0, stream>>>(
        xb, scale + b * CC, shift + b * CC, ht);
    // fused QKV conv -> qt[n][m], kt[n][m], vv[c][j] (V transposed in-epilogue)
    qkv_conv<<<dim3(CC / 64, NN / 128), 256, 0, stream>>>(
        ht, wq16, wk16, wv16, bq, bk, bv, qt, kt, vv);
    // S = (qt . kt^T) * rs : M=N=4096, K=512
    gemm_tn<128, 128, 4, 4, 2, 0, false, false, false>
        <<<dim3(NN / 128, NN / 128), 256, 0, stream>>>(
            qt, CC, kt, CC, S, NN, nullptr, nullptr, CC, rs, 0);
    softmax_bf16<<<NN, 256, 0, stream>>>(S);
    // PV split-K=8, BN=256 (single logical S pass): part[z][i][c]
    gemm_tn<64, 256, 4, 4, 4, 0, false, false, true>
        <<<dim3(CC / 256, NN / 64, 8), 256, 0, stream>>>(
            S, NN, vv, NN, part, CC, nullptr, nullptr, NN / 8, 1.0f, NN * CC);
    reduce8<<<(NN * CC / 8) / 256, 256, 0, stream>>>(part, ot);
    // proj + bias + residual, fp32 out: M=512(co), N=4096, K=512
    gemm_tn<64, 64, 2, 2, 2, 1, true, true, false>
        <<<dim3(NN / 64, CC / 64), 256, 0, stream>>>(
            wp16, CC, ot, CC, out + (size_t)b * CC * NN, NN, bp, xb, CC, 1.0f, 0);
  }
}

// Round 6
// 1096.115 us; speedup vs baseline: 6.5717x; 1.0146x over previous
//
#include <hip/hip_runtime.h>
#include <math.h>

#define BB 8
#define CC 512
#define GG 32
#define CPG 16
#define NN 4096
#define EPSV 1e-5f

typedef __attribute__((ext_vector_type(8))) short bf16x8;
typedef __attribute__((ext_vector_type(4))) float f32x4;

__device__ __forceinline__ unsigned short f2bf(float f) {
  union { float f; unsigned u; } v;
  v.f = f;
  unsigned r = v.u + 0x7FFFu + ((v.u >> 16) & 1u);  // RNE
  return (unsigned short)(r >> 16);
}

// ---------------------------------------------------------------------------
// GroupNorm stats. 256 blocks x 1024 threads (16 waves/CU) — R5 showed the
// 256-thread version latency-bound at 0.73 TB/s / 8.7% occupancy.
// ---------------------------------------------------------------------------
__global__ __launch_bounds__(1024) void gn_stats(
    const float* __restrict__ x, const float* __restrict__ gamma,
    const float* __restrict__ beta, float* __restrict__ scale,
    float* __restrict__ shift) {
  int bg = blockIdx.x;
  int b = bg / GG, g = bg % GG;
  const float* base = x + ((size_t)b * CC + (size_t)g * CPG) * NN;
  int t = threadIdx.x;
  float s = 0.f, ss = 0.f;
  const float4* b4 = (const float4*)base;
  const int n4 = CPG * NN / 4;  // 16384 float4 -> 16 per thread
  for (int idx = t; idx < n4; idx += 1024) {
    float4 v = b4[idx];
    s += v.x + v.y + v.z + v.w;
    ss += v.x * v.x + v.y * v.y + v.z * v.z + v.w * v.w;
  }
  __shared__ float ls[1024], lss[1024];
  ls[t] = s; lss[t] = ss;
  __syncthreads();
  for (int o = 512; o > 0; o >>= 1) {
    if (t < o) { ls[t] += ls[t + o]; lss[t] += lss[t + o]; }
    __syncthreads();
  }
  if (t < CPG) {
    const float invn = 1.0f / (float)(CPG * NN);
    float mean = ls[0] * invn;
    float var = lss[0] * invn - mean * mean;
    float rstd = rsqrtf(var + EPSV);
    int c = g * CPG + t;
    float sc = rstd * gamma[c];
    scale[b * CC + c] = sc;
    shift[b * CC + c] = beta[c] - mean * sc;
  }
}

// ---------------------------------------------------------------------------
// All four fp32 [512x512] weights -> bf16 in one launch (blockIdx.y selects)
// ---------------------------------------------------------------------------
__global__ __launch_bounds__(256) void cvt_bf16_all(
    const float* __restrict__ w0, const float* __restrict__ w1,
    const float* __restrict__ w2, const float* __restrict__ w3,
    unsigned short* __restrict__ d0, unsigned short* __restrict__ d1,
    unsigned short* __restrict__ d2, unsigned short* __restrict__ d3) {
  const float* src;
  unsigned short* dst;
  switch (blockIdx.y) {
    case 0: src = w0; dst = d0; break;
    case 1: src = w1; dst = d1; break;
    case 2: src = w2; dst = d2; break;
    default: src = w3; dst = d3; break;
  }
  int i = blockIdx.x * 256 + threadIdx.x;
  float4 v = ((const float4*)src)[i];
  ushort4 o;
  o.x = f2bf(v.x); o.y = f2bf(v.y); o.z = f2bf(v.z); o.w = f2bf(v.w);
  ((ushort4*)dst)[i] = o;
}

// ---------------------------------------------------------------------------
// GN-apply + transpose for ONE batch: ht[n][c] = x[c][n]*scale[c]+shift[c]
// ---------------------------------------------------------------------------
__global__ __launch_bounds__(256) void gn_apply_t(
    const float* __restrict__ xb, const float* __restrict__ scb,
    const float* __restrict__ shb, unsigned short* __restrict__ ht) {
  int c0 = blockIdx.y * 64;
  int n0 = blockIdx.x * 64;
  __shared__ unsigned short tile[64][65];
  int t = threadIdx.x;
  int tn = t & 63, t4 = t >> 6;
#pragma unroll
  for (int r = 0; r < 16; ++r) {
    int c = r * 4 + t4;
    float sc = scb[c0 + c];
    float sh = shb[c0 + c];
    float v = xb[(size_t)(c0 + c) * NN + n0 + tn];
    tile[c][tn] = f2bf(v * sc + sh);
  }
  __syncthreads();
#pragma unroll
  for (int r = 0; r < 16; ++r) {
    int n = r * 4 + t4;
    ht[(size_t)(n0 + n) * CC + c0 + tn] = tile[tn][n];
  }
}

// ---------------------------------------------------------------------------
// Fused QKV conv (one batch): qt[n][cout], kt[n][cout]; V stored transposed
// into vv[cout][n] via ushort4 (4 consecutive spatial rows per lane).
// ---------------------------------------------------------------------------
__global__ __launch_bounds__(256) void qkv_conv(
    const unsigned short* __restrict__ A, const unsigned short* __restrict__ W0,
    const unsigned short* __restrict__ W1, const unsigned short* __restrict__ W2,
    const float* __restrict__ b0, const float* __restrict__ b1,
    const float* __restrict__ b2, unsigned short* __restrict__ C0,
    unsigned short* __restrict__ C1, unsigned short* __restrict__ vv) {
  __shared__ unsigned short Al[128 * 32];
  __shared__ unsigned short Bl0[64 * 32];
  __shared__ unsigned short Bl1[64 * 32];
  __shared__ unsigned short Bl2[64 * 32];
  const int m0 = blockIdx.y * 128;
  const int n0 = blockIdx.x * 64;
  const int t = threadIdx.x;
  const int wave = t >> 6, lane = t & 63;
  const int ln15 = lane & 15, quad = lane >> 4;
  const int wm0 = (wave >> 1) * 64;
  const int wn0 = (wave & 1) * 32;
  const int srow = lane >> 2;
  const int scol = (lane & 3) * 8;

  f32x4 acc0[4][2], acc1[4][2], acc2[4][2];
#pragma unroll
  for (int i = 0; i < 4; ++i)
#pragma unroll
    for (int j = 0; j < 2; ++j)
#pragma unroll
      for (int r = 0; r < 4; ++r) {
        acc0[i][j][r] = 0.f; acc1[i][j][r] = 0.f; acc2[i][j][r] = 0.f;
      }

  for (int k0 = 0; k0 < CC; k0 += 32) {
#pragma unroll
    for (int r = wave; r < 8; r += 4) {
      const unsigned short* gp = A + (size_t)(m0 + r * 16 + srow) * CC + k0 + scol;
      __builtin_amdgcn_global_load_lds(
          (const __attribute__((address_space(1))) void*)gp,
          (__attribute__((address_space(3))) void*)(Al + r * 16 * 32), 16, 0, 0);
    }
    {
      int r = wave;
      const unsigned short* gp = W0 + (size_t)(n0 + r * 16 + srow) * CC + k0 + scol;
      __builtin_amdgcn_global_load_lds(
          (const __attribute__((address_space(1))) void*)gp,
          (__attribute__((address_space(3))) void*)(Bl0 + r * 16 * 32), 16, 0, 0);
      gp = W1 + (size_t)(n0 + r * 16 + srow) * CC + k0 + scol;
      __builtin_amdgcn_global_load_lds(
          (const __attribute__((address_space(1))) void*)gp,
          (__attribute__((address_space(3))) void*)(Bl1 + r * 16 * 32), 16, 0, 0);
      gp = W2 + (size_t)(n0 + r * 16 + srow) * CC + k0 + scol;
      __builtin_amdgcn_global_load_lds(
          (const __attribute__((address_space(1))) void*)gp,
          (__attribute__((address_space(3))) void*)(Bl2 + r * 16 * 32), 16, 0, 0);
    }
    __syncthreads();
    bf16x8 af[4], bf0[2], bf1[2], bf2[2];
#pragma unroll
    for (int i = 0; i < 4; ++i)
      af[i] = *(const bf16x8*)(Al + (wm0 + i * 16 + ln15) * 32 + quad * 8);
#pragma unroll
    for (int j = 0; j < 2; ++j) {
      bf0[j] = *(const bf16x8*)(Bl0 + (wn0 + j * 16 + ln15) * 32 + quad * 8);
      bf1[j] = *(const bf16x8*)(Bl1 + (wn0 + j * 16 + ln15) * 32 + quad * 8);
      bf2[j] = *(const bf16x8*)(Bl2 + (wn0 + j * 16 + ln15) * 32 + quad * 8);
    }
#pragma unroll
    for (int i = 0; i < 4; ++i)
#pragma unroll
      for (int j = 0; j < 2; ++j) {
        acc0[i][j] = __builtin_amdgcn_mfma_f32_16x16x32_bf16(af[i], bf0[j], acc0[i][j], 0, 0, 0);
        acc1[i][j] = __builtin_amdgcn_mfma_f32_16x16x32_bf16(af[i], bf1[j], acc1[i][j], 0, 0, 0);
        acc2[i][j] = __builtin_amdgcn_mfma_f32_16x16x32_bf16(af[i], bf2[j], acc2[i][j], 0, 0, 0);
      }
    __syncthreads();
  }
#pragma unroll
  for (int i = 0; i < 4; ++i)
#pragma unroll
    for (int j = 0; j < 2; ++j) {
      int col = n0 + wn0 + j * 16 + ln15;
      float c0b = b0[col], c1b = b1[col], c2b = b2[col];
      int row0 = m0 + wm0 + i * 16 + quad * 4;
#pragma unroll
      for (int r = 0; r < 4; ++r) {
        size_t off = (size_t)(row0 + r) * CC + col;
        C0[off] = f2bf(acc0[i][j][r] + c0b);
        C1[off] = f2bf(acc1[i][j][r] + c1b);
      }
      ushort4 pk;
      pk.x = f2bf(acc2[i][j][0] + c2b);
      pk.y = f2bf(acc2[i][j][1] + c2b);
      pk.z = f2bf(acc2[i][j][2] + c2b);
      pk.w = f2bf(acc2[i][j][3] + c2b);
      *(ushort4*)(vv + (size_t)col * NN + row0) = pk;
    }
}

// ---------------------------------------------------------------------------
// Generic TN bf16 MFMA GEMM:
//   C[m][n] = scale * sum_k A[m][k]*B[n][k]  (+bias, +resid)
// CSTG: coalesced bf16 epilogue via LDS restage (requires BM=128, BN=128,
//       4 waves 2x2, bf16 out, no bias/resid) — used for the QK->S GEMM.
// PART: split-K over blockIdx.z, bf16 partial planes.
// ---------------------------------------------------------------------------
template <int BM, int BN, int WM, int WN, int WX, int BIAS, bool RESID,
          bool OUTF32, bool PART, bool CSTG>
__global__ __launch_bounds__(256) void gemm_tn(
    const unsigned short* __restrict__ A, int lda,
    const unsigned short* __restrict__ B, int ldb,
    void* __restrict__ Cout, int ldc, const float* __restrict__ bias,
    const float* __restrict__ resid, int K, float scale, int plane) {
  __shared__ unsigned short smem[BM * 32 + BN * 32];
  unsigned short* Al = smem;
  unsigned short* Bl = smem + BM * 32;
  const int m0 = blockIdx.y * BM;
  const int n0 = blockIdx.x * BN;
  const size_t koff = PART ? (size_t)blockIdx.z * K : 0;
  const int t = threadIdx.x;
  const int wave = t >> 6, lane = t & 63;
  const int ln15 = lane & 15, quad = lane >> 4;
  const int wm0 = (wave / WX) * (WM * 16);
  const int wn0 = (wave % WX) * (WN * 16);
  const int srow = lane >> 2;
  const int scol = (lane & 3) * 8;

  f32x4 acc[WM][WN];
#pragma unroll
  for (int i = 0; i < WM; ++i)
#pragma unroll
    for (int j = 0; j < WN; ++j) {
      acc[i][j][0] = 0.f; acc[i][j][1] = 0.f;
      acc[i][j][2] = 0.f; acc[i][j][3] = 0.f;
    }

  for (int k0 = 0; k0 < K; k0 += 32) {
#pragma unroll
    for (int r = wave; r < BM / 16; r += 4) {
      const unsigned short* gp =
          A + (size_t)(m0 + r * 16 + srow) * lda + koff + k0 + scol;
      __builtin_amdgcn_global_load_lds(
          (const __attribute__((address_space(1))) void*)gp,
          (__attribute__((address_space(3))) void*)(Al + r * 16 * 32), 16, 0, 0);
    }
#pragma unroll
    for (int r = wave; r < BN / 16; r += 4) {
      const unsigned short* gp =
          B + (size_t)(n0 + r * 16 + srow) * ldb + koff + k0 + scol;
      __builtin_amdgcn_global_load_lds(
          (const __attribute__((address_space(1))) void*)gp,
          (__attribute__((address_space(3))) void*)(Bl + r * 16 * 32), 16, 0, 0);
    }
    __syncthreads();
    bf16x8 af[WM], bfr[WN];
#pragma unroll
    for (int i = 0; i < WM; ++i)
      af[i] = *(const bf16x8*)(Al + (wm0 + i * 16 + ln15) * 32 + quad * 8);
#pragma unroll
    for (int j = 0; j < WN; ++j)
      bfr[j] = *(const bf16x8*)(Bl + (wn0 + j * 16 + ln15) * 32 + quad * 8);
#pragma unroll
    for (int i = 0; i < WM; ++i)
#pragma unroll
      for (int j = 0; j < WN; ++j)
        acc[i][j] = __builtin_amdgcn_mfma_f32_16x16x32_bf16(af[i], bfr[j],
                                                            acc[i][j], 0, 0, 0);
    __syncthreads();
  }

  if (CSTG) {
    // Coalesced bf16 epilogue: restage C through LDS in two 64-row halves.
    // Wave w owns global rows wm0..wm0+63 (wm0 = (w>>1)*64): half h = w>>1.
#pragma unroll
    for (int h = 0; h < 2; ++h) {
      if ((wave >> 1) == h) {
#pragma unroll
        for (int i = 0; i < WM; ++i)
#pragma unroll
          for (int j = 0; j < WN; ++j) {
            int lcol = wn0 + j * 16 + ln15;
#pragma unroll
            for (int r = 0; r < 4; ++r) {
              int lrow = i * 16 + quad * 4 + r;  // 0..63 within half
              smem[lrow * BN + lcol] = f2bf(acc[i][j][r] * scale);
            }
          }
      }
      __syncthreads();
      // stream out 64 x BN bf16 as uint4 (16B/lane, fully coalesced)
#pragma unroll
      for (int u = 0; u < 64 * BN / 8 / 256; ++u) {
        int s = (t + u * 256) * 8;
        int lr = s / BN, lc = s % BN;
        uint4 d = *(const uint4*)(smem + s);
        *(uint4*)((unsigned short*)Cout + (size_t)(m0 + h * 64 + lr) * ldc +
                  n0 + lc) = d;
      }
      __syncthreads();
    }
    return;
  }

#pragma unroll
  for (int i = 0; i < WM; ++i) {
#pragma unroll
    for (int j = 0; j < WN; ++j) {
      int col = n0 + wn0 + j * 16 + ln15;
      float bcol = (BIAS == 2) ? bias[col] : 0.f;
#pragma unroll
      for (int r = 0; r < 4; ++r) {
        int row = m0 + wm0 + i * 16 + quad * 4 + r;
        float v = acc[i][j][r] * scale;
        if (BIAS == 1) v += bias[row];
        if (BIAS == 2) v += bcol;
        if (RESID) v += resid[(size_t)row * ldc + col];
        if (PART)
          ((unsigned short*)Cout)[(size_t)blockIdx.z * plane +
                                  (size_t)row * ldc + col] = f2bf(v);
        else if (OUTF32)
          ((float*)Cout)[(size_t)row * ldc + col] = v;
        else
          ((unsigned short*)Cout)[(size_t)row * ldc + col] = f2bf(v);
      }
    }
  }
}

// ---------------------------------------------------------------------------
// Split-K reduce: ot (bf16) = sum over 8 bf16 planes (fp32 accumulate)
// ---------------------------------------------------------------------------
__global__ __launch_bounds__(256) void reduce8(
    const unsigned short* __restrict__ part, unsigned short* __restrict__ ot) {
  const size_t plane = (size_t)NN * CC;
  size_t e = ((size_t)blockIdx.x * 256 + threadIdx.x) * 8;
  float acc[8] = {};
#pragma unroll
  for (int p = 0; p < 8; ++p) {
    uint4 d = *(const uint4*)(part + p * plane + e);
    unsigned w[4] = {d.x, d.y, d.z, d.w};
#pragma unroll
    for (int q = 0; q < 4; ++q) {
      union { unsigned u; float f; } lo, hi;
      lo.u = w[q] << 16;
      hi.u = w[q] & 0xFFFF0000u;
      acc[2 * q] += lo.f;
      acc[2 * q + 1] += hi.f;
    }
  }
  unsigned o[4];
#pragma unroll
  for (int q = 0; q < 4; ++q) {
    unsigned short b0 = f2bf(acc[2 * q]);
    unsigned short b1 = f2bf(acc[2 * q + 1]);
    o[q] = ((unsigned)b1 << 16) | (unsigned)b0;
  }
  uint4 o4; o4.x = o[0]; o4.y = o[1]; o4.z = o[2]; o4.w = o[3];
  *(uint4*)(ot + e) = o4;
}

// ---------------------------------------------------------------------------
// In-place bf16 row softmax (fp32 math)
// ---------------------------------------------------------------------------
__global__ __launch_bounds__(256) void softmax_bf16(unsigned short* __restrict__ S) {
  int i = blockIdx.x;
  uint4* row4 = (uint4*)(S + (size_t)i * NN);
  int t = threadIdx.x;
  uint4 d[2];
  d[0] = row4[t];
  d[1] = row4[t + 256];
  float f[16];
#pragma unroll
  for (int h = 0; h < 2; ++h) {
    unsigned w[4] = {d[h].x, d[h].y, d[h].z, d[h].w};
#pragma unroll
    for (int q = 0; q < 4; ++q) {
      union { unsigned u; float f; } lo, hi;
      lo.u = w[q] << 16;
      hi.u = w[q] & 0xFFFF0000u;
      f[h * 8 + 2 * q] = lo.f;
      f[h * 8 + 2 * q + 1] = hi.f;
    }
  }
  float m = -1e30f;
#pragma unroll
  for (int e = 0; e < 16; ++e) m = fmaxf(m, f[e]);
  __shared__ float red[256];
  red[t] = m;
  __syncthreads();
  for (int o = 128; o > 0; o >>= 1) {
    if (t < o) red[t] = fmaxf(red[t], red[t + o]);
    __syncthreads();
  }
  m = red[0];
  __syncthreads();
  float s = 0.f;
#pragma unroll
  for (int e = 0; e < 16; ++e) {
    f[e] = __expf(f[e] - m);
    s += f[e];
  }
  red[t] = s;
  __syncthreads();
  for (int o = 128; o > 0; o >>= 1) {
    if (t < o) red[t] += red[t + o];
    __syncthreads();
  }
  float inv = 1.0f / red[0];
#pragma unroll
  for (int h = 0; h < 2; ++h) {
    unsigned w[4];
#pragma unroll
    for (int q = 0; q < 4; ++q) {
      unsigned short b0 = f2bf(f[h * 8 + 2 * q] * inv);
      unsigned short b1 = f2bf(f[h * 8 + 2 * q + 1] * inv);
      w[q] = ((unsigned)b1 << 16) | (unsigned)b0;
    }
    uint4 o4; o4.x = w[0]; o4.y = w[1]; o4.z = w[2]; o4.w = w[3];
    row4[t + h * 256] = o4;
  }
}

// ---------------------------------------------------------------------------
extern "C" void kernel_launch(void* const* d_in, const int* in_sizes, int n_in,
                              void* d_out, int out_size, void* d_ws,
                              size_t ws_size, hipStream_t stream) {
  const float* x = (const float*)d_in[0];
  const float* gamma = (const float*)d_in[1];
  const float* beta = (const float*)d_in[2];
  const float* Wq = (const float*)d_in[3];
  const float* bq = (const float*)d_in[4];
  const float* Wk = (const float*)d_in[5];
  const float* bk = (const float*)d_in[6];
  const float* Wv = (const float*)d_in[7];
  const float* bv = (const float*)d_in[8];
  const float* Wp = (const float*)d_in[9];
  const float* bp = (const float*)d_in[10];
  float* out = (float*)d_out;

  // workspace (~86 MiB, under the 96 MiB proven-safe budget)
  char* p = (char*)d_ws;
  const size_t CN2 = (size_t)NN * CC * 2;                   // 4 MiB
  unsigned short* ht = (unsigned short*)p; p += CN2;
  unsigned short* qt = (unsigned short*)p; p += CN2;
  unsigned short* kt = (unsigned short*)p; p += CN2;
  unsigned short* vv = (unsigned short*)p; p += CN2;
  unsigned short* ot = (unsigned short*)p; p += CN2;
  unsigned short* S  = (unsigned short*)p; p += (size_t)NN * NN * 2;   // 32 MiB
  unsigned short* part = (unsigned short*)p; p += (size_t)8 * NN * CC * 2; // 32
  unsigned short* w16 = (unsigned short*)p; p += (size_t)4 * CC * CC * 2;
  unsigned short* wq16 = w16;
  unsigned short* wk16 = w16 + (size_t)CC * CC;
  unsigned short* wv16 = w16 + (size_t)2 * CC * CC;
  unsigned short* wp16 = w16 + (size_t)3 * CC * CC;
  float* scale = (float*)p; p += BB * CC * 4;
  float* shift = (float*)p;

  const float rs = 0.04419417382415922f;  // 1/sqrt(512)

  gn_stats<<<BB * GG, 1024, 0, stream>>>(x, gamma, beta, scale, shift);
  cvt_bf16_all<<<dim3(256, 4), 256, 0, stream>>>(Wq, Wk, Wv, Wp, wq16, wk16,
                                                 wv16, wp16);

  for (int b = 0; b < BB; ++b) {
    const float* xb = x + (size_t)b * CC * NN;
    gn_apply_t<<<dim3(NN / 64, CC / 64), 256, 0, stream>>>(
        xb, scale + b * CC, shift + b * CC, ht);
    qkv_conv<<<dim3(CC / 64, NN / 128), 256, 0, stream>>>(
        ht, wq16, wk16, wv16, bq, bk, bv, qt, kt, vv);
    // S = (qt . kt^T) * rs, coalesced LDS-staged epilogue
    gemm_tn<128, 128, 4, 4, 2, 0, false, false, false, true>
        <<<dim3(NN / 128, NN / 128), 256, 0, stream>>>(
            qt, CC, kt, CC, S, NN, nullptr, nullptr, CC, rs, 0);
    softmax_bf16<<<NN, 256, 0, stream>>>(S);
    // PV split-K=8, BN=256: part[z][i][c]
    gemm_tn<64, 256, 4, 4, 4, 0, false, false, true, false>
        <<<dim3(CC / 256, NN / 64, 8), 256, 0, stream>>>(
            S, NN, vv, NN, part, CC, nullptr, nullptr, NN / 8, 1.0f, NN * CC);
    reduce8<<<(NN * CC / 8) / 256, 256, 0, stream>>>(part, ot);
    // proj + bias + residual, fp32 out
    gemm_tn<64, 64, 2, 2, 2, 1, true, true, false, false>
        <<<dim3(NN / 64, CC / 64), 256, 0, stream>>>(
            wp16, CC, ot, CC, out + (size_t)b * CC * NN, NN, bp, xb, CC, 1.0f, 0);
  }
}